// Round 2
// baseline (1235.196 us; speedup 1.0000x reference)
//
#include <hip/hip_runtime.h>
#include <stdint.h>

typedef unsigned short u16;
typedef __bf16 bf16x8 __attribute__((ext_vector_type(8)));
typedef float f32x4 __attribute__((ext_vector_type(4)));

#define D_MODEL 2048
#define NHEADS 16
#define DK 128
#define DFF 5504
#define BB 2
#define SS 2048
#define MTOK 4096  // B*S

__device__ __forceinline__ u16 f2bf(float f){
  union { float f; uint32_t u; } v; v.f = f;
  uint32_t r = v.u + 0x7fffu + ((v.u >> 16) & 1u);
  return (u16)(r >> 16);
}
__device__ __forceinline__ float bf2f(u16 u){
  union { uint32_t u; float f; } v; v.u = ((uint32_t)u) << 16;
  return v.f;
}

// ---- fp32 W[K][N] -> bf16 Wt[N][K] (LDS-tiled transpose+convert) ----
__global__ __launch_bounds__(256) void k_transpose_w(const float* __restrict__ W,
                                                     u16* __restrict__ Wt, int K, int N){
  __shared__ float tile[32][33];
  int n0 = blockIdx.x * 32, k0 = blockIdx.y * 32;
  int tx = threadIdx.x, ty = threadIdx.y;  // (32,8)
  #pragma unroll
  for (int r = 0; r < 4; ++r)
    tile[ty + r*8][tx] = W[(size_t)(k0 + ty + r*8) * N + n0 + tx];
  __syncthreads();
  #pragma unroll
  for (int r = 0; r < 4; ++r)
    Wt[(size_t)(n0 + ty + r*8) * K + k0 + tx] = f2bf(tile[tx][ty + r*8]);
}

// ---- per-head V transpose: Vt[(bh*128+d)*S + s] = V[(b*S+s)*D + h*128+d] ----
__global__ __launch_bounds__(256) void k_transpose_v(const u16* __restrict__ V,
                                                     u16* __restrict__ Vt){
  __shared__ u16 tile[32][33];
  int s0 = blockIdx.x * 32;
  int bh = blockIdx.y >> 2, dt = blockIdx.y & 3;
  int b = bh >> 4, h = bh & 15;
  int tx = threadIdx.x, ty = threadIdx.y;
  #pragma unroll
  for (int r = 0; r < 4; ++r)
    tile[ty + r*8][tx] = V[(size_t)(b*SS + s0 + ty + r*8) * D_MODEL + h*DK + dt*32 + tx];
  __syncthreads();
  #pragma unroll
  for (int r = 0; r < 4; ++r)
    Vt[(size_t)(bh*DK + dt*32 + ty + r*8) * SS + s0 + tx] = tile[tx][ty + r*8];
}

// ---- RMSNorm: fp32 row -> bf16 row (row = 2048) ----
__global__ __launch_bounds__(256) void k_rmsnorm(const float* __restrict__ X,
                                                 const float* __restrict__ g,
                                                 u16* __restrict__ out){
  int row = blockIdx.x, tid = threadIdx.x;
  const float* x = X + (size_t)row * D_MODEL;
  float4 a = ((const float4*)x)[tid*2];
  float4 b = ((const float4*)x)[tid*2+1];
  float ss = a.x*a.x + a.y*a.y + a.z*a.z + a.w*a.w
           + b.x*b.x + b.y*b.y + b.z*b.z + b.w*b.w;
  #pragma unroll
  for (int m = 1; m < 64; m <<= 1) ss += __shfl_xor(ss, m, 64);
  __shared__ float red[4];
  if ((tid & 63) == 0) red[tid >> 6] = ss;
  __syncthreads();
  float tot = red[0] + red[1] + red[2] + red[3];
  float sc = rsqrtf(tot * (1.0f / D_MODEL) + 1e-6f);
  float4 ga = ((const float4*)g)[tid*2];
  float4 gb = ((const float4*)g)[tid*2+1];
  uint32_t w0 = f2bf(a.x*sc*ga.x) | ((uint32_t)f2bf(a.y*sc*ga.y) << 16);
  uint32_t w1 = f2bf(a.z*sc*ga.z) | ((uint32_t)f2bf(a.w*sc*ga.w) << 16);
  uint32_t w2 = f2bf(b.x*sc*gb.x) | ((uint32_t)f2bf(b.y*sc*gb.y) << 16);
  uint32_t w3 = f2bf(b.z*sc*gb.z) | ((uint32_t)f2bf(b.w*sc*gb.w) << 16);
  ((uint4*)(out + (size_t)row * D_MODEL))[tid] = make_uint4(w0, w1, w2, w3);
}

// ---- bf16 GEMM, m97 structure: C[M][N] = A[M][K] * Bt[N][K]^T (+epilogue) ----
// EPI 0: bf16 out, +bias       (QKV)
// EPI 1: f32 out, +bias +res   (O proj)
// EPI 2: bf16 out, plain       (W1)
// EPI 3: f32 out, +res         (W2, final)
// EPI 4: bf16 out, silu(aux)*acc, in-place on aux (W3 fused with silu-mul)
template<int EPI>
__global__ __launch_bounds__(256) void k_gemm_bt(
    const u16* __restrict__ A, const u16* __restrict__ Bt,
    const float* __restrict__ bias, const float* __restrict__ res,
    const u16* __restrict__ aux,
    void* __restrict__ Cout, int M, int N, int K)
{
  __shared__ __align__(16) u16 As[128*32];
  __shared__ __align__(16) u16 Bs[128*32];
  int tid = threadIdx.x;
  int m0 = blockIdx.y * 128, n0 = blockIdx.x * 128;
  int lane = tid & 63, wave = tid >> 6;
  int wr = wave >> 1, wc = wave & 1;
  int lrow = lane & 15, lhi = lane >> 4;
  f32x4 acc[4][4] = {};
  int srow = tid >> 2;
  int scol = (tid & 3) * 8;
  const int nk = K >> 5;
  for (int kt = 0; kt < nk; ++kt){
    int k0 = kt << 5;
    #pragma unroll
    for (int c = 0; c < 2; ++c){
      int r = c*64 + srow;
      __builtin_amdgcn_global_load_lds(
        (const __attribute__((address_space(1))) void*)(A + (size_t)(m0 + r)*K + k0 + scol),
        (__attribute__((address_space(3))) void*)(&As[r*32 + scol]), 16, 0, 0);
      __builtin_amdgcn_global_load_lds(
        (const __attribute__((address_space(1))) void*)(Bt + (size_t)(n0 + r)*K + k0 + scol),
        (__attribute__((address_space(3))) void*)(&Bs[r*32 + scol]), 16, 0, 0);
    }
    __syncthreads();
    bf16x8 af[4], bfv[4];
    #pragma unroll
    for (int i = 0; i < 4; ++i){
      af[i]  = *(const bf16x8*)(&As[(wr*64 + i*16 + lrow)*32 + lhi*8]);
      bfv[i] = *(const bf16x8*)(&Bs[(wc*64 + i*16 + lrow)*32 + lhi*8]);
    }
    #pragma unroll
    for (int i = 0; i < 4; ++i)
      #pragma unroll
      for (int j = 0; j < 4; ++j)
        acc[i][j] = __builtin_amdgcn_mfma_f32_16x16x32_bf16(af[i], bfv[j], acc[i][j], 0, 0, 0);
    __syncthreads();
  }
  #pragma unroll
  for (int i = 0; i < 4; ++i){
    #pragma unroll
    for (int j = 0; j < 4; ++j){
      int col = n0 + wc*64 + j*16 + lrow;
      float bv = 0.f;
      if constexpr (EPI == 0 || EPI == 1) bv = bias[col];
      #pragma unroll
      for (int q = 0; q < 4; ++q){
        int row = m0 + wr*64 + i*16 + lhi*4 + q;
        size_t idx = (size_t)row*N + col;
        float v = acc[i][j][q] + bv;
        if constexpr (EPI == 1 || EPI == 3) v += res[idx];
        if constexpr (EPI == 4){
          float a0 = bf2f(aux[idx]);
          v = a0 / (1.f + __expf(-a0)) * v;
        }
        if constexpr (EPI == 0 || EPI == 2 || EPI == 4) ((u16*)Cout)[idx] = f2bf(v);
        else ((float*)Cout)[idx] = v;
      }
    }
  }
}

// ---- causal flash attention: 64 q-rows/block, 4 waves x 16 rows ----
__global__ __launch_bounds__(256) void k_attn(
    const u16* __restrict__ Q, const u16* __restrict__ Kb,
    const u16* __restrict__ Vt, u16* __restrict__ O)
{
  int tid = threadIdx.x, lane = tid & 63, wave = tid >> 6;
  int lrow = lane & 15, lhi = lane >> 4;
  int bh = blockIdx.y, b = bh >> 4, h = bh & 15;
  int qs = blockIdx.x * 64;
  int qrow = qs + wave * 16;
  __shared__ __align__(16) u16 P_lds[4][16*32];
  u16* pw = &P_lds[wave][0];
  const float scale = 0.08838834764831845f;  // 1/sqrt(128)

  bf16x8 qf[4];
  const u16* qbase = Q + (size_t)(b*SS + qrow + lrow)*D_MODEL + h*DK + lhi*8;
  #pragma unroll
  for (int dc = 0; dc < 4; ++dc) qf[dc] = *(const bf16x8*)(qbase + dc*32);

  f32x4 accO[8] = {};
  float mr[4] = {-1e30f,-1e30f,-1e30f,-1e30f};
  float lr[4] = {0.f,0.f,0.f,0.f};

  int ntiles = (qs + 64) >> 5;
  for (int kt = 0; kt < ntiles; ++kt){
    int kv0 = kt << 5;
    const u16* kbase = Kb + (size_t)(b*SS + kv0 + lrow)*D_MODEL + h*DK + lhi*8;
    f32x4 sf[2];
    #pragma unroll
    for (int half = 0; half < 2; ++half){
      f32x4 a = {};
      #pragma unroll
      for (int dc = 0; dc < 4; ++dc){
        bf16x8 kf = *(const bf16x8*)(kbase + (size_t)(half*16)*D_MODEL + dc*32);
        a = __builtin_amdgcn_mfma_f32_16x16x32_bf16(qf[dc], kf, a, 0, 0, 0);
      }
      sf[half] = a;
    }
    float alpha[4], p0a[4], p1a[4];
    #pragma unroll
    for (int q = 0; q < 4; ++q){
      int qg = qrow + lhi*4 + q;
      float s0 = sf[0][q] * scale;
      float s1 = sf[1][q] * scale;
      if (kv0 + lrow > qg)      s0 = -1e30f;
      if (kv0 + 16 + lrow > qg) s1 = -1e30f;
      float mx = fmaxf(s0, s1);
      mx = fmaxf(mx, __shfl_xor(mx, 1, 64));
      mx = fmaxf(mx, __shfl_xor(mx, 2, 64));
      mx = fmaxf(mx, __shfl_xor(mx, 4, 64));
      mx = fmaxf(mx, __shfl_xor(mx, 8, 64));
      float mnew = fmaxf(mr[q], mx);
      float al = __expf(mr[q] - mnew);
      float p0 = __expf(s0 - mnew);
      float p1 = __expf(s1 - mnew);
      float sm = p0 + p1;
      sm += __shfl_xor(sm, 1, 64);
      sm += __shfl_xor(sm, 2, 64);
      sm += __shfl_xor(sm, 4, 64);
      sm += __shfl_xor(sm, 8, 64);
      lr[q] = lr[q]*al + sm;
      mr[q] = mnew;
      alpha[q] = al; p0a[q] = p0; p1a[q] = p1;
    }
    #pragma unroll
    for (int f = 0; f < 8; ++f)
      #pragma unroll
      for (int q = 0; q < 4; ++q) accO[f][q] *= alpha[q];
    #pragma unroll
    for (int q = 0; q < 4; ++q){
      pw[(lhi*4 + q)*32 + lrow]      = f2bf(p0a[q]);
      pw[(lhi*4 + q)*32 + 16 + lrow] = f2bf(p1a[q]);
    }
    __syncthreads();
    bf16x8 pa = *(const bf16x8*)(pw + lrow*32 + lhi*8);
    const u16* vbase = Vt + ((size_t)bh*DK + lrow)*SS + kv0 + lhi*8;
    #pragma unroll
    for (int f = 0; f < 8; ++f){
      bf16x8 vf = *(const bf16x8*)(vbase + (size_t)(f*16)*SS);
      accO[f] = __builtin_amdgcn_mfma_f32_16x16x32_bf16(pa, vf, accO[f], 0, 0, 0);
    }
    __syncthreads();
  }
  #pragma unroll
  for (int f = 0; f < 8; ++f){
    #pragma unroll
    for (int q = 0; q < 4; ++q){
      int row = b*SS + qrow + lhi*4 + q;
      int col = h*DK + f*16 + lrow;
      O[(size_t)row*D_MODEL + col] = f2bf(accO[f][q] / lr[q]);
    }
  }
}

extern "C" void kernel_launch(void* const* d_in, const int* in_sizes, int n_in,
                              void* d_out, int out_size, void* d_ws, size_t ws_size,
                              hipStream_t stream)
{
  (void)in_sizes; (void)n_in; (void)out_size;
  const float* x  = (const float*)d_in[0];
  const float* wq = (const float*)d_in[2];
  const float* bq = (const float*)d_in[3];
  const float* wk = (const float*)d_in[4];
  const float* bk = (const float*)d_in[5];
  const float* wv = (const float*)d_in[6];
  const float* bv = (const float*)d_in[7];
  const float* wo = (const float*)d_in[8];
  const float* bo = (const float*)d_in[9];
  const float* g1 = (const float*)d_in[10];
  const float* g2 = (const float*)d_in[11];
  const float* w1 = (const float*)d_in[12];
  const float* w3 = (const float*)d_in[13];  // w3 precedes w2 in dict order
  const float* w2 = (const float*)d_in[14];
  float* out = (float*)d_out;

  // ---- workspace layout (byte offsets), lifetime-aliased; total 176.5 MiB ----
  const size_t MB = 1u << 20;
  const size_t WFF = (size_t)D_MODEL * DFF * sizeof(u16);  // 22,544,384 B
  const size_t NEED = 112*MB + 3*WFF;                      // 185,073,664 B
  if (ws_size < NEED) return;  // diagnostic guard: too-small ws -> clean absmax fail
  char* ws = (char*)d_ws;
  u16* bufA = (u16*)(ws + 0);        // 16 MiB: nbf1 -> aob -> nbf2
  u16* qbf  = (u16*)(ws + 16*MB);    // 16 MiB
  u16* kbf  = (u16*)(ws + 32*MB);    // 16 MiB
  u16* vbf  = (u16*)(ws + 48*MB);    // 16 MiB
  u16* h1   = qbf;                   // 45.1 MiB, aliases qbf+kbf+vbf after attn
  u16* wqt  = (u16*)(ws + 64*MB);    // 8 MiB
  u16* wkt  = (u16*)(ws + 72*MB);
  u16* wvt  = (u16*)(ws + 80*MB);
  u16* wot  = (u16*)(ws + 88*MB);
  u16* vtb  = (u16*)(ws + 96*MB);    // 16 MiB
  u16* w1t  = (u16*)(ws + 112*MB);   // 21.5 MiB each
  u16* w3t  = (u16*)(ws + 112*MB + WFF);
  u16* w2t  = (u16*)(ws + 112*MB + 2*WFF);
  // fp32 residual x1 lives in d_out (written by O-proj, read by rmsnorm2 + final GEMM)

  dim3 tb(32, 8);
  k_transpose_w<<<dim3(64,64), tb, 0, stream>>>(wq, wqt, D_MODEL, D_MODEL);
  k_transpose_w<<<dim3(64,64), tb, 0, stream>>>(wk, wkt, D_MODEL, D_MODEL);
  k_transpose_w<<<dim3(64,64), tb, 0, stream>>>(wv, wvt, D_MODEL, D_MODEL);
  k_transpose_w<<<dim3(64,64), tb, 0, stream>>>(wo, wot, D_MODEL, D_MODEL);
  k_transpose_w<<<dim3(DFF/32,64), tb, 0, stream>>>(w1, w1t, D_MODEL, DFF);
  k_transpose_w<<<dim3(DFF/32,64), tb, 0, stream>>>(w3, w3t, D_MODEL, DFF);
  k_transpose_w<<<dim3(64,DFF/32), tb, 0, stream>>>(w2, w2t, DFF, D_MODEL);

  k_rmsnorm<<<MTOK, 256, 0, stream>>>(x, g1, bufA);
  k_gemm_bt<0><<<dim3(16,32), 256, 0, stream>>>(bufA, wqt, bq, nullptr, nullptr, qbf, MTOK, D_MODEL, D_MODEL);
  k_gemm_bt<0><<<dim3(16,32), 256, 0, stream>>>(bufA, wkt, bk, nullptr, nullptr, kbf, MTOK, D_MODEL, D_MODEL);
  k_gemm_bt<0><<<dim3(16,32), 256, 0, stream>>>(bufA, wvt, bv, nullptr, nullptr, vbf, MTOK, D_MODEL, D_MODEL);
  k_transpose_v<<<dim3(SS/32, 128), tb, 0, stream>>>(vbf, vtb);
  k_attn<<<dim3(SS/64, BB*NHEADS), 256, 0, stream>>>(qbf, kbf, vtb, bufA);
  k_gemm_bt<1><<<dim3(16,32), 256, 0, stream>>>(bufA, wot, bo, x, nullptr, out, MTOK, D_MODEL, D_MODEL);
  k_rmsnorm<<<MTOK, 256, 0, stream>>>(out, g2, bufA);
  k_gemm_bt<2><<<dim3(DFF/128,32), 256, 0, stream>>>(bufA, w1t, nullptr, nullptr, nullptr, h1, MTOK, DFF, D_MODEL);
  k_gemm_bt<4><<<dim3(DFF/128,32), 256, 0, stream>>>(bufA, w3t, nullptr, nullptr, h1, h1, MTOK, DFF, D_MODEL);
  k_gemm_bt<3><<<dim3(16,32), 256, 0, stream>>>(h1, w2t, nullptr, out, nullptr, out, MTOK, D_MODEL, DFF);
}